// Round 4
// baseline (519.336 us; speedup 1.0000x reference)
//
#include <hip/hip_runtime.h>
#include <hip/hip_cooperative_groups.h>

namespace cg = cooperative_groups;

#define HIDDEN 64
#define NB 32
#define HSTR 72        // LDS H-tile row stride in shorts: %8==0 (16B align for b128)
#define PRE_BLOCKS 256 // cooperative prep grid: 1 block/CU, trivially co-resident
#define PRE_THREADS 256

typedef __attribute__((ext_vector_type(8))) short bf16x8;
typedef __attribute__((ext_vector_type(4))) float f32x4;

// ---- bf16 helpers (RNE) ----
static __device__ __forceinline__ unsigned short f2bf(float x) {
    union { float f; unsigned u; } v; v.f = x;
    unsigned r = v.u + 0x7fffu + ((v.u >> 16) & 1u);
    return (unsigned short)(r >> 16);
}
static __device__ __forceinline__ float bf2f(unsigned short s) {
    union { unsigned u; float f; } v; v.u = ((unsigned)s) << 16;
    return v.f;
}

// ---------------------------------------------------------------------------
// Cooperative prep kernel: fuses {memset, featpack+hist, scan x3, scatter}
// (6 dispatches -> 1; each dispatch boundary cost ~10-15 us of launch/serialize
// overhead per round-3 arithmetic). Phases separated by grid.sync().
// Requires N <= PRE_BLOCKS*PRE_THREADS (= 65536; problem has N = 50000).
// ---------------------------------------------------------------------------
__global__ __launch_bounds__(PRE_THREADS) void prep_kernel(
    const float* __restrict__ scalar,     // [N,64]
    const float* __restrict__ vector,     // [N,3,64]
    const int*   __restrict__ edge_index, // [2,E]
    int* __restrict__ counts,             // [N]
    ushort4* __restrict__ feat,           // [N*64]
    int* __restrict__ offsets,            // [N+1]
    int* __restrict__ cursors,            // [N]
    int* __restrict__ blocksums,          // [PRE_BLOCKS]
    int* __restrict__ cols,               // [E]
    int* __restrict__ eperm,              // [E]
    int N, int E, int total, int do_feat)
{
    cg::grid_group grid = cg::this_grid();
    __shared__ int tmp[PRE_THREADS];

    const int t   = threadIdx.x;
    const int gid = blockIdx.x * PRE_THREADS + t;
    const int nth = gridDim.x * PRE_THREADS;

    // phase 0: zero counts
    for (int i = gid; i < N; i += nth) counts[i] = 0;
    grid.sync();

    // phase 1: histogram + feature pack
    for (int i = gid; i < E; i += nth)
        atomicAdd(&counts[edge_index[i]], 1);
    if (do_feat) {
        for (int i = gid; i < total; i += nth) {
            const int n = i >> 6, l = i & 63;
            const float* vp = vector + (size_t)n * 192 + l;
            ushort4 o;
            o.x = f2bf(scalar[i]);
            o.y = f2bf(vp[0]);
            o.z = f2bf(vp[64]);
            o.w = f2bf(vp[128]);
            feat[i] = o;
        }
    }
    grid.sync();

    // phase 2: block-local scan over this block's 256-element chunk
    const int base = blockIdx.x * PRE_THREADS;
    int v = (base + t < N) ? counts[base + t] : 0;
    tmp[t] = v;
    __syncthreads();
    for (int off = 1; off < PRE_THREADS; off <<= 1) {
        int x = (t >= off) ? tmp[t - off] : 0;
        __syncthreads();
        tmp[t] += x;
        __syncthreads();
    }
    const int excl = tmp[t] - v;           // exclusive within block
    if (t == PRE_THREADS - 1) blocksums[blockIdx.x] = tmp[t];
    grid.sync();

    // phase 3: block 0 scans the PRE_BLOCKS partials (exclusive)
    if (blockIdx.x == 0) {
        int b = blocksums[t];
        tmp[t] = b;
        __syncthreads();
        for (int off = 1; off < PRE_THREADS; off <<= 1) {
            int x = (t >= off) ? tmp[t - off] : 0;
            __syncthreads();
            tmp[t] += x;
            __syncthreads();
        }
        blocksums[t] = tmp[t] - b;
    }
    grid.sync();

    // phase 4: write offsets + cursors
    if (base + t < N) {
        const int o = excl + blocksums[blockIdx.x];
        offsets[base + t] = o;
        cursors[base + t] = o;
    }
    if (gid == 0) offsets[N] = E;
    grid.sync();

    // phase 5: scatter -- claim CSR slot p; record source col + forward perm
    for (int i = gid; i < E; i += nth) {
        int p = atomicAdd(&cursors[edge_index[i]], 1);
        cols[p] = edge_index[E + i];
        eperm[p] = i;
    }
}

// ---------------------------------------------------------------------------
// Phase A (MFMA, CSR slot order): gathers edge_length rows via eperm
// (L3-resident -> round-3 FETCH 33 MB), writes W rows SEQUENTIALLY
// (round-3 WRITE exactly 125 MB, no write-allocate amplification).
// W[p][0..63] = scalar-MLP weights, W[p][64..127] = vector-MLP weights (bf16).
// ---------------------------------------------------------------------------
__global__ __launch_bounds__(256) void mlp_mfma_kernel(
    const float* __restrict__ edge_length,   // [E,32]
    const int*   __restrict__ eperm,         // [E] edge id at CSR slot p
    const float* __restrict__ sw1, const float* __restrict__ sb1,
    const float* __restrict__ sw2, const float* __restrict__ sb2,
    const float* __restrict__ vw1, const float* __restrict__ vb1,
    const float* __restrict__ vw2, const float* __restrict__ vb2,
    unsigned short* __restrict__ W,          // [E,128] bf16, CSR row order
    int E, int nchunks)
{
    __shared__ short Hs[4][64 * HSTR];       // per-wave staging

    const int t    = threadIdx.x;
    const int lane = t & 63;
    const int wid  = t >> 6;
    const int quad = lane >> 4;
    const int l16  = lane & 15;
    short* Hw = Hs[wid];

    const float* w1p[2] = {sw1, vw1};
    const float* b1p[2] = {sb1, vb1};
    const float* w2p[2] = {sw2, vw2};
    const float* b2p[2] = {sb2, vb2};

    // ---- weight B-frags resident in VGPRs ----
    bf16x8 w1f[2][4];
    bf16x8 w2f[2][2][4];
    float  b1v[2][4], b2v[2][4];
    #pragma unroll
    for (int m = 0; m < 2; ++m) {
        #pragma unroll
        for (int nt = 0; nt < 4; ++nt) {
            const int col = nt * 16 + l16;
            #pragma unroll
            for (int j = 0; j < 8; ++j)
                w1f[m][nt][j] = (short)f2bf(w1p[m][(quad * 8 + j) * HIDDEN + col]);
            #pragma unroll
            for (int kk = 0; kk < 2; ++kk) {
                #pragma unroll
                for (int j = 0; j < 8; ++j)
                    w2f[m][kk][nt][j] = (short)f2bf(w2p[m][(kk * 32 + quad * 8 + j) * HIDDEN + col]);
            }
            b1v[m][nt] = b1p[m][col];
            b2v[m][nt] = b2p[m][col];
        }
    }

    const int wave_g = blockIdx.x * 4 + wid;
    const int nwaves = gridDim.x * 4;

    for (int c = wave_g; c < nchunks; c += nwaves) {
        const int j0 = c * 64;

        // ---- A-frags: 64 CSR slots -> gathered edge rows (L3-resident) ----
        bf16x8 af[4];
        #pragma unroll
        for (int mt = 0; mt < 4; ++mt) {
            int p = j0 + mt * 16 + l16;
            if (p >= E) p = E - 1;
            const int e = eperm[p];
            const float* r = edge_length + (size_t)e * NB + quad * 8;
            float4 u0 = *(const float4*)r;
            float4 u1 = *(const float4*)(r + 4);
            af[mt][0] = (short)f2bf(u0.x); af[mt][1] = (short)f2bf(u0.y);
            af[mt][2] = (short)f2bf(u0.z); af[mt][3] = (short)f2bf(u0.w);
            af[mt][4] = (short)f2bf(u1.x); af[mt][5] = (short)f2bf(u1.y);
            af[mt][6] = (short)f2bf(u1.z); af[mt][7] = (short)f2bf(u1.w);
        }

        #pragma unroll
        for (int m = 0; m < 2; ++m) {
            // ---- layer 1 + SiLU -> LDS bf16 ----
            #pragma unroll
            for (int mt = 0; mt < 4; ++mt) {
                #pragma unroll
                for (int nt = 0; nt < 4; ++nt) {
                    f32x4 cf = {b1v[m][nt], b1v[m][nt], b1v[m][nt], b1v[m][nt]};
                    cf = __builtin_amdgcn_mfma_f32_16x16x32_bf16(af[mt], w1f[m][nt], cf, 0, 0, 0);
                    #pragma unroll
                    for (int r4 = 0; r4 < 4; ++r4) {
                        float x = cf[r4];
                        // silu via fast rcp: result is rounded to bf16 anyway
                        x = x * __builtin_amdgcn_rcpf(1.0f + __expf(-x));
                        const int row = mt * 16 + quad * 4 + r4;
                        Hw[row * HSTR + nt * 16 + l16] = (short)f2bf(x);
                    }
                }
            }

            // ---- layer 2 -> LDS bf16 ----
            #pragma unroll
            for (int mt = 0; mt < 4; ++mt) {
                const int arow = mt * 16 + l16;
                bf16x8 a0 = *(const bf16x8*)(Hw + arow * HSTR + quad * 8);
                bf16x8 a1 = *(const bf16x8*)(Hw + arow * HSTR + 32 + quad * 8);
                #pragma unroll
                for (int nt = 0; nt < 4; ++nt) {
                    f32x4 cf = {b2v[m][nt], b2v[m][nt], b2v[m][nt], b2v[m][nt]};
                    cf = __builtin_amdgcn_mfma_f32_16x16x32_bf16(a1, w2f[m][1][nt], cf, 0, 0, 0);
                    cf = __builtin_amdgcn_mfma_f32_16x16x32_bf16(a0, w2f[m][0][nt], cf, 0, 0, 0);
                    #pragma unroll
                    for (int r4 = 0; r4 < 4; ++r4) {
                        const int row = mt * 16 + quad * 4 + r4;
                        Hw[row * HSTR + nt * 16 + l16] = (short)f2bf(cf[r4]);
                    }
                }
            }

            // ---- store: 8 lanes per edge row, 16 B/lane, SEQUENTIAL dest ----
            #pragma unroll
            for (int i = 0; i < 8; ++i) {
                const int row = i * 8 + (lane >> 3);
                bf16x8 v = *(const bf16x8*)(Hw + row * HSTR + (lane & 7) * 8);
                if (j0 + row < E)
                    *(bf16x8*)(W + (size_t)(j0 + row) * 128 + m * 64 + (lane & 7) * 8) = v;
            }
        }
    }
}

// ---------------------------------------------------------------------------
// Phase B (bf16 feat path): one wave per node; 4-deep software pipeline.
// Round-3 evidence: 73.5 us at 44% BW, VALUBusy 25% -> latency-bound with
// only 1 edge (4 loads) in flight per wave. 4 named stages (static indexing
// per rule #20), OOB stages clamped + zero-weighted (wave-uniform selects).
// ---------------------------------------------------------------------------
__global__ __launch_bounds__(256) void node_kernel_feat(
    const ushort4* __restrict__ feat,       // [N*64] bf16 {s,v0,v1,v2}
    const int* __restrict__ offsets,        // [N+1]
    const int* __restrict__ cols,           // [E] source column per CSR slot
    const unsigned short* __restrict__ W,   // [E,128] bf16, CSR order
    float* __restrict__ out_scalar,
    float* __restrict__ out_vector,
    int N)
{
    const int lane = threadIdx.x & 63;
    const int wave = blockIdx.x * 4 + (threadIdx.x >> 6);
    const int nw   = gridDim.x * 4;

    for (int n = wave; n < N; n += nw) {
        const int beg = offsets[n];
        const int end = offsets[n + 1];

        float as = 0.0f, a0 = 0.0f, a1 = 0.0f, a2 = 0.0f;

        if (beg < end) {
            float wsA, wvA, sA, v0A, v1A, v2A;
            float wsB, wvB, sB, v0B, v1B, v2B;
            float wsC, wvC, sC, v0C, v1C, v2C;
            float wsD, wvD, sD, v0D, v1D, v2D;

#define LOADX(WS, WV, S, V0, V1, V2, jj) {                                   \
            const int _ok = (jj) < end;                                       \
            const int _j  = _ok ? (jj) : (end - 1);                           \
            const unsigned short* _wp = W + (size_t)_j * 128;                 \
            WS = _ok ? bf2f(_wp[lane]) : 0.0f;                                \
            WV = _ok ? bf2f(_wp[64 + lane]) : 0.0f;                           \
            const ushort4 _f = feat[(size_t)cols[_j] * 64 + lane];            \
            S = bf2f(_f.x); V0 = bf2f(_f.y); V1 = bf2f(_f.z); V2 = bf2f(_f.w); }

#define CONSX(WS, WV, S, V0, V1, V2) {                                        \
            as = fmaf(S,  WS, as);                                            \
            a0 = fmaf(V0, WV, a0);                                            \
            a1 = fmaf(V1, WV, a1);                                            \
            a2 = fmaf(V2, WV, a2); }

            LOADX(wsA, wvA, sA, v0A, v1A, v2A, beg);
            LOADX(wsB, wvB, sB, v0B, v1B, v2B, beg + 1);
            LOADX(wsC, wvC, sC, v0C, v1C, v2C, beg + 2);
            LOADX(wsD, wvD, sD, v0D, v1D, v2D, beg + 3);

            int j = beg;
            for (; j + 4 < end; j += 4) {
                CONSX(wsA, wvA, sA, v0A, v1A, v2A);
                LOADX(wsA, wvA, sA, v0A, v1A, v2A, j + 4);
                CONSX(wsB, wvB, sB, v0B, v1B, v2B);
                LOADX(wsB, wvB, sB, v0B, v1B, v2B, j + 5);
                CONSX(wsC, wvC, sC, v0C, v1C, v2C);
                LOADX(wsC, wvC, sC, v0C, v1C, v2C, j + 6);
                CONSX(wsD, wvD, sD, v0D, v1D, v2D);
                LOADX(wsD, wvD, sD, v0D, v1D, v2D, j + 7);
            }
            // stages hold j..j+3 (zero-weighted where >= end)
            CONSX(wsA, wvA, sA, v0A, v1A, v2A);
            CONSX(wsB, wvB, sB, v0B, v1B, v2B);
            CONSX(wsC, wvC, sC, v0C, v1C, v2C);
            CONSX(wsD, wvD, sD, v0D, v1D, v2D);
#undef LOADX
#undef CONSX
        }

        out_scalar[(size_t)n * HIDDEN + lane] = as;
        float* ov = out_vector + (size_t)n * 3 * HIDDEN;
        ov[lane]       = a0;
        ov[64 + lane]  = a1;
        ov[128 + lane] = a2;
    }
}

// Fallback (fp32 feature gathers) if workspace can't hold the feat table.
__global__ __launch_bounds__(256) void node_kernel_f32(
    const float* __restrict__ scalar,
    const float* __restrict__ vector,
    const int* __restrict__ offsets,
    const int* __restrict__ cols,
    const unsigned short* __restrict__ W,
    float* __restrict__ out_scalar,
    float* __restrict__ out_vector,
    int N)
{
    const int lane = threadIdx.x & 63;
    const int wave = blockIdx.x * 4 + (threadIdx.x >> 6);
    const int nw   = gridDim.x * 4;

    for (int n = wave; n < N; n += nw) {
        const int beg = offsets[n];
        const int end = offsets[n + 1];
        float as = 0.0f, a0 = 0.0f, a1 = 0.0f, a2 = 0.0f;
        for (int j = beg; j < end; ++j) {
            const unsigned short* wp = W + (size_t)j * 128;
            const float w_s = bf2f(wp[lane]);
            const float w_v = bf2f(wp[64 + lane]);
            const int c = cols[j];
            const float* sp = scalar + (size_t)c * HIDDEN;
            const float* vp = vector + (size_t)c * 3 * HIDDEN;
            as = fmaf(sp[lane],       w_s, as);
            a0 = fmaf(vp[lane],       w_v, a0);
            a1 = fmaf(vp[64 + lane],  w_v, a1);
            a2 = fmaf(vp[128 + lane], w_v, a2);
        }
        out_scalar[(size_t)n * HIDDEN + lane] = as;
        float* ov = out_vector + (size_t)n * 3 * HIDDEN;
        ov[lane]       = a0;
        ov[64 + lane]  = a1;
        ov[128 + lane] = a2;
    }
}

extern "C" void kernel_launch(void* const* d_in, const int* in_sizes, int n_in,
                              void* d_out, int out_size, void* d_ws, size_t ws_size,
                              hipStream_t stream) {
    const float* scalar      = (const float*)d_in[0];
    const float* vector      = (const float*)d_in[1];
    // d_in[2] = edge_sh (unused by reference)
    const float* edge_length = (const float*)d_in[3];
    const int*   edge_index  = (const int*)d_in[4];
    const float* sw1 = (const float*)d_in[5];
    const float* sb1 = (const float*)d_in[6];
    const float* sw2 = (const float*)d_in[7];
    const float* sb2 = (const float*)d_in[8];
    const float* vw1 = (const float*)d_in[9];
    const float* vb1 = (const float*)d_in[10];
    const float* vw2 = (const float*)d_in[11];
    const float* vb2 = (const float*)d_in[12];

    const int N = in_sizes[0] / HIDDEN;       // 50000
    const int E = in_sizes[4] / 2;            // 500000

    float* out_scalar = (float*)d_out;
    float* out_vector = (float*)d_out + (size_t)N * HIDDEN;

    // ---- workspace layout ----
    size_t off = 0;
    unsigned short* W = (unsigned short*)d_ws;           // [E,128] bf16 = 128 MB
    off += (size_t)E * 128 * 2;
    int* cols = (int*)((char*)d_ws + off);               // [E] = 2 MB
    off += (size_t)E * 4;
    int* eperm = (int*)((char*)d_ws + off);              // [E] = 2 MB
    off += (size_t)E * 4;
    int* ib = (int*)((char*)d_ws + off);
    int* counts    = ib;                                  // [N]
    int* offsets   = ib + N;                              // [N+1]
    int* cursors   = ib + 2 * N + 1;                      // [N]
    int* blocksums = ib + 3 * N + 1;                      // [PRE_BLOCKS]
    off += ((size_t)3 * N + 1 + PRE_BLOCKS) * 4;
    off = (off + 15) & ~(size_t)15;
    ushort4* feat = (ushort4*)((char*)d_ws + off);        // [N*64] = 25.6 MB
    const bool use_feat = (off + (size_t)N * 64 * 8) <= ws_size;

    // ---- fused prep (memset+featpack+hist+scan+scatter) in ONE coop launch ----
    {
        int total   = N * 64;
        int do_feat = use_feat ? 1 : 0;
        void* args[] = {
            (void*)&scalar, (void*)&vector, (void*)&edge_index,
            (void*)&counts, (void*)&feat, (void*)&offsets, (void*)&cursors,
            (void*)&blocksums, (void*)&cols, (void*)&eperm,
            (void*)&N, (void*)&E, (void*)&total, (void*)&do_feat
        };
        hipLaunchCooperativeKernel((void*)prep_kernel,
                                   dim3(PRE_BLOCKS), dim3(PRE_THREADS),
                                   args, 0, stream);
    }

    // Phase A: MLP via MFMA over CSR slots; gathered reads, sequential writes.
    const int nchunks = (E + 63) / 64;
    mlp_mfma_kernel<<<1024, 256, 0, stream>>>(
        edge_length, eperm,
        sw1, sb1, sw2, sb2, vw1, vb1, vw2, vb2,
        W, E, nchunks);

    // Phase B: sequential W streaming, 4-deep pipelined gathers.
    const int ngrid = (N + 3) / 4;
    if (use_feat) {
        node_kernel_feat<<<ngrid, 256, 0, stream>>>(
            feat, offsets, cols, W, out_scalar, out_vector, N);
    } else {
        node_kernel_f32<<<ngrid, 256, 0, stream>>>(
            scalar, vector, offsets, cols, W, out_scalar, out_vector, N);
    }
}

// Round 5
// 343.124 us; speedup vs baseline: 1.5136x; 1.5136x over previous
//
#include <hip/hip_runtime.h>

#define HIDDEN 64
#define NB 32
#define SCAN_BLOCK 1024
#define HSTR 72   // LDS H-tile row stride in shorts: %8==0 (16B align for b128)

typedef __attribute__((ext_vector_type(8))) short bf16x8;
typedef __attribute__((ext_vector_type(4))) float f32x4;

// ---- bf16 helpers (RNE) ----
static __device__ __forceinline__ unsigned short f2bf(float x) {
    union { float f; unsigned u; } v; v.f = x;
    unsigned r = v.u + 0x7fffu + ((v.u >> 16) & 1u);
    return (unsigned short)(r >> 16);
}
static __device__ __forceinline__ float bf2f(unsigned short s) {
    union { unsigned u; float f; } v; v.u = ((unsigned)s) << 16;
    return v.f;
}

// ---------------------------------------------------------------------------
// Feature pack: feat[n][lane] = {scalar, v0, v1, v2} as bf16x4 (8 B).
// Fused histogram: first E threads also count destination rows (counts must
// be pre-zeroed). Grid covers max(total, E).
// ---------------------------------------------------------------------------
__global__ __launch_bounds__(256) void featpack_kernel(
    const float* __restrict__ scalar,   // [N,64]
    const float* __restrict__ vector,   // [N,3,64]
    const int*   __restrict__ edge_index, // [2,E] (row part used for hist)
    int* __restrict__ counts,           // [N] pre-zeroed
    ushort4* __restrict__ feat,         // [N*64]
    int total, int E, int do_feat)
{
    int i = blockIdx.x * 256 + threadIdx.x;
    if (i < E) atomicAdd(&counts[edge_index[i]], 1);
    if (!do_feat || i >= total) return;
    const int n = i >> 6, l = i & 63;
    const float* vp = vector + (size_t)n * 192 + l;
    ushort4 o;
    o.x = f2bf(scalar[i]);
    o.y = f2bf(vp[0]);
    o.z = f2bf(vp[64]);
    o.w = f2bf(vp[128]);
    feat[i] = o;
}

// ---------------------------------------------------------------------------
// CSR scan: 3-pass multi-block.
// ---------------------------------------------------------------------------
__global__ __launch_bounds__(SCAN_BLOCK) void scan_pass1(
    const int* __restrict__ counts, int* __restrict__ partial,
    int* __restrict__ blocksums, int N)
{
    __shared__ int tmp[SCAN_BLOCK];
    const int t = threadIdx.x;
    const int gid = blockIdx.x * SCAN_BLOCK + t;
    int v = (gid < N) ? counts[gid] : 0;
    tmp[t] = v;
    __syncthreads();
    for (int off = 1; off < SCAN_BLOCK; off <<= 1) {
        int x = (t >= off) ? tmp[t - off] : 0;
        __syncthreads();
        tmp[t] += x;
        __syncthreads();
    }
    if (gid < N) partial[gid] = tmp[t] - v;
    if (t == SCAN_BLOCK - 1) blocksums[blockIdx.x] = tmp[t];
}

__global__ __launch_bounds__(64) void scan_pass2(int* __restrict__ blocksums, int nb)
{
    const int t = threadIdx.x;
    int v = (t < nb) ? blocksums[t] : 0;
    int s = v;
    #pragma unroll
    for (int off = 1; off < 64; off <<= 1) {
        int x = __shfl_up(s, off, 64);
        if (t >= off) s += x;
    }
    if (t < nb) blocksums[t] = s - v;   // exclusive
}

__global__ __launch_bounds__(SCAN_BLOCK) void scan_pass3(
    const int* __restrict__ partial, const int* __restrict__ blocksums,
    int* __restrict__ offsets, int* __restrict__ cursors, int N, int E)
{
    const int gid = blockIdx.x * SCAN_BLOCK + threadIdx.x;
    if (gid < N) {
        int o = partial[gid] + blocksums[blockIdx.x];
        offsets[gid] = o;
        cursors[gid] = o;
    }
    if (blockIdx.x == 0 && threadIdx.x == 0) offsets[N] = E;
}

// Scatter: per edge, claim CSR slot p; record the source column at p and the
// forward permutation eperm[p] = e so phase A can READ edges in CSR order
// (random reads of L3-resident edge_length) and WRITE W sequentially.
__global__ __launch_bounds__(256) void scatter_kernel(
    const int* __restrict__ edge_index, int* __restrict__ cursors,
    int* __restrict__ cols, int* __restrict__ eperm, int E)
{
    int i = blockIdx.x * 256 + threadIdx.x;
    if (i < E) {
        int p = atomicAdd(&cursors[edge_index[i]], 1);
        cols[p] = edge_index[E + i];
        eperm[p] = i;
    }
}

// ---------------------------------------------------------------------------
// Phase A (MFMA, CSR slot order): gathers edge_length rows via eperm
// (L3-resident -> round-3 FETCH 33 MB), writes W rows SEQUENTIALLY
// (round-3 WRITE exactly 125 MB, no write-allocate amplification).
// W[p][0..63] = scalar-MLP weights, W[p][64..127] = vector-MLP weights (bf16).
// ---------------------------------------------------------------------------
__global__ __launch_bounds__(256) void mlp_mfma_kernel(
    const float* __restrict__ edge_length,   // [E,32]
    const int*   __restrict__ eperm,         // [E] edge id at CSR slot p
    const float* __restrict__ sw1, const float* __restrict__ sb1,
    const float* __restrict__ sw2, const float* __restrict__ sb2,
    const float* __restrict__ vw1, const float* __restrict__ vb1,
    const float* __restrict__ vw2, const float* __restrict__ vb2,
    unsigned short* __restrict__ W,          // [E,128] bf16, CSR row order
    int E, int nchunks)
{
    __shared__ short Hs[4][64 * HSTR];       // per-wave staging

    const int t    = threadIdx.x;
    const int lane = t & 63;
    const int wid  = t >> 6;
    const int quad = lane >> 4;
    const int l16  = lane & 15;
    short* Hw = Hs[wid];

    const float* w1p[2] = {sw1, vw1};
    const float* b1p[2] = {sb1, vb1};
    const float* w2p[2] = {sw2, vw2};
    const float* b2p[2] = {sb2, vb2};

    // ---- weight B-frags resident in VGPRs ----
    bf16x8 w1f[2][4];
    bf16x8 w2f[2][2][4];
    float  b1v[2][4], b2v[2][4];
    #pragma unroll
    for (int m = 0; m < 2; ++m) {
        #pragma unroll
        for (int nt = 0; nt < 4; ++nt) {
            const int col = nt * 16 + l16;
            #pragma unroll
            for (int j = 0; j < 8; ++j)
                w1f[m][nt][j] = (short)f2bf(w1p[m][(quad * 8 + j) * HIDDEN + col]);
            #pragma unroll
            for (int kk = 0; kk < 2; ++kk) {
                #pragma unroll
                for (int j = 0; j < 8; ++j)
                    w2f[m][kk][nt][j] = (short)f2bf(w2p[m][(kk * 32 + quad * 8 + j) * HIDDEN + col]);
            }
            b1v[m][nt] = b1p[m][col];
            b2v[m][nt] = b2p[m][col];
        }
    }

    const int wave_g = blockIdx.x * 4 + wid;
    const int nwaves = gridDim.x * 4;

    for (int c = wave_g; c < nchunks; c += nwaves) {
        const int j0 = c * 64;

        // ---- A-frags: 64 CSR slots -> gathered edge rows (L3-resident) ----
        bf16x8 af[4];
        #pragma unroll
        for (int mt = 0; mt < 4; ++mt) {
            int p = j0 + mt * 16 + l16;
            if (p >= E) p = E - 1;
            const int e = eperm[p];
            const float* r = edge_length + (size_t)e * NB + quad * 8;
            float4 u0 = *(const float4*)r;
            float4 u1 = *(const float4*)(r + 4);
            af[mt][0] = (short)f2bf(u0.x); af[mt][1] = (short)f2bf(u0.y);
            af[mt][2] = (short)f2bf(u0.z); af[mt][3] = (short)f2bf(u0.w);
            af[mt][4] = (short)f2bf(u1.x); af[mt][5] = (short)f2bf(u1.y);
            af[mt][6] = (short)f2bf(u1.z); af[mt][7] = (short)f2bf(u1.w);
        }

        #pragma unroll
        for (int m = 0; m < 2; ++m) {
            // ---- layer 1 + SiLU -> LDS bf16 ----
            #pragma unroll
            for (int mt = 0; mt < 4; ++mt) {
                #pragma unroll
                for (int nt = 0; nt < 4; ++nt) {
                    f32x4 cf = {b1v[m][nt], b1v[m][nt], b1v[m][nt], b1v[m][nt]};
                    cf = __builtin_amdgcn_mfma_f32_16x16x32_bf16(af[mt], w1f[m][nt], cf, 0, 0, 0);
                    #pragma unroll
                    for (int r4 = 0; r4 < 4; ++r4) {
                        float x = cf[r4];
                        // silu via fast rcp: result is rounded to bf16 anyway
                        x = x * __builtin_amdgcn_rcpf(1.0f + __expf(-x));
                        const int row = mt * 16 + quad * 4 + r4;
                        Hw[row * HSTR + nt * 16 + l16] = (short)f2bf(x);
                    }
                }
            }

            // ---- layer 2 -> LDS bf16 ----
            #pragma unroll
            for (int mt = 0; mt < 4; ++mt) {
                const int arow = mt * 16 + l16;
                bf16x8 a0 = *(const bf16x8*)(Hw + arow * HSTR + quad * 8);
                bf16x8 a1 = *(const bf16x8*)(Hw + arow * HSTR + 32 + quad * 8);
                #pragma unroll
                for (int nt = 0; nt < 4; ++nt) {
                    f32x4 cf = {b2v[m][nt], b2v[m][nt], b2v[m][nt], b2v[m][nt]};
                    cf = __builtin_amdgcn_mfma_f32_16x16x32_bf16(a1, w2f[m][1][nt], cf, 0, 0, 0);
                    cf = __builtin_amdgcn_mfma_f32_16x16x32_bf16(a0, w2f[m][0][nt], cf, 0, 0, 0);
                    #pragma unroll
                    for (int r4 = 0; r4 < 4; ++r4) {
                        const int row = mt * 16 + quad * 4 + r4;
                        Hw[row * HSTR + nt * 16 + l16] = (short)f2bf(cf[r4]);
                    }
                }
            }

            // ---- store: 8 lanes per edge row, 16 B/lane, SEQUENTIAL dest ----
            #pragma unroll
            for (int i = 0; i < 8; ++i) {
                const int row = i * 8 + (lane >> 3);
                bf16x8 v = *(const bf16x8*)(Hw + row * HSTR + (lane & 7) * 8);
                if (j0 + row < E)
                    *(bf16x8*)(W + (size_t)(j0 + row) * 128 + m * 64 + (lane & 7) * 8) = v;
            }
        }
    }
}

// ---------------------------------------------------------------------------
// Phase B (bf16 feat path): one wave per node; round-3's proven 1-ahead
// structure, with the cols[j] pointer chase removed: cols[beg..end] is
// CONTIGUOUS in CSR order, so each lane loads one entry per 64-edge chunk
// and per-edge columns come from a __shfl broadcast (VALU, no memory).
// All prefetch addresses are then register-computable.
// ---------------------------------------------------------------------------
__global__ __launch_bounds__(256) void node_kernel_feat(
    const ushort4* __restrict__ feat,       // [N*64] bf16 {s,v0,v1,v2}
    const int* __restrict__ offsets,        // [N+1]
    const int* __restrict__ cols,           // [E] source column per CSR slot
    const unsigned short* __restrict__ W,   // [E,128] bf16, CSR order
    float* __restrict__ out_scalar,
    float* __restrict__ out_vector,
    int N)
{
    const int lane = threadIdx.x & 63;
    const int wave = blockIdx.x * 4 + (threadIdx.x >> 6);
    const int nw   = gridDim.x * 4;

    for (int n = wave; n < N; n += nw) {
        const int beg = offsets[n];
        const int end = offsets[n + 1];

        float as = 0.0f, a0 = 0.0f, a1 = 0.0f, a2 = 0.0f;

        for (int base = beg; base < end; base += 64) {
            const int cnt = (end - base < 64) ? (end - base) : 64;

            // one coalesced load per chunk: lane's CSR column
            int mycol = 0;
            if (lane < cnt) mycol = cols[base + lane];

            // prologue: edge k=0
            const int c0 = __shfl(mycol, 0, 64);
            const unsigned short* wp0 = W + (size_t)base * 128;
            float ws = bf2f(wp0[lane]);
            float wv = bf2f(wp0[64 + lane]);
            ushort4 f = feat[(size_t)c0 * 64 + lane];

            for (int k = 0; k < cnt; ++k) {
                const int kn = (k + 1 < cnt) ? k + 1 : k;
                const int cn = __shfl(mycol, kn, 64);
                const unsigned short* wpn = W + (size_t)(base + kn) * 128;
                const float wsn = bf2f(wpn[lane]);
                const float wvn = bf2f(wpn[64 + lane]);
                const ushort4 fn = feat[(size_t)cn * 64 + lane];

                as = fmaf(bf2f(f.x), ws, as);
                a0 = fmaf(bf2f(f.y), wv, a0);
                a1 = fmaf(bf2f(f.z), wv, a1);
                a2 = fmaf(bf2f(f.w), wv, a2);

                ws = wsn; wv = wvn; f = fn;
            }
        }

        out_scalar[(size_t)n * HIDDEN + lane] = as;
        float* ov = out_vector + (size_t)n * 3 * HIDDEN;
        ov[lane]       = a0;
        ov[64 + lane]  = a1;
        ov[128 + lane] = a2;
    }
}

// Fallback (fp32 feature gathers) if workspace can't hold the feat table.
__global__ __launch_bounds__(256) void node_kernel_f32(
    const float* __restrict__ scalar,
    const float* __restrict__ vector,
    const int* __restrict__ offsets,
    const int* __restrict__ cols,
    const unsigned short* __restrict__ W,
    float* __restrict__ out_scalar,
    float* __restrict__ out_vector,
    int N)
{
    const int lane = threadIdx.x & 63;
    const int wave = blockIdx.x * 4 + (threadIdx.x >> 6);
    const int nw   = gridDim.x * 4;

    for (int n = wave; n < N; n += nw) {
        const int beg = offsets[n];
        const int end = offsets[n + 1];
        float as = 0.0f, a0 = 0.0f, a1 = 0.0f, a2 = 0.0f;
        for (int j = beg; j < end; ++j) {
            const unsigned short* wp = W + (size_t)j * 128;
            const float w_s = bf2f(wp[lane]);
            const float w_v = bf2f(wp[64 + lane]);
            const int c = cols[j];
            const float* sp = scalar + (size_t)c * HIDDEN;
            const float* vp = vector + (size_t)c * 3 * HIDDEN;
            as = fmaf(sp[lane],       w_s, as);
            a0 = fmaf(vp[lane],       w_v, a0);
            a1 = fmaf(vp[64 + lane],  w_v, a1);
            a2 = fmaf(vp[128 + lane], w_v, a2);
        }
        out_scalar[(size_t)n * HIDDEN + lane] = as;
        float* ov = out_vector + (size_t)n * 3 * HIDDEN;
        ov[lane]       = a0;
        ov[64 + lane]  = a1;
        ov[128 + lane] = a2;
    }
}

extern "C" void kernel_launch(void* const* d_in, const int* in_sizes, int n_in,
                              void* d_out, int out_size, void* d_ws, size_t ws_size,
                              hipStream_t stream) {
    const float* scalar      = (const float*)d_in[0];
    const float* vector      = (const float*)d_in[1];
    // d_in[2] = edge_sh (unused by reference)
    const float* edge_length = (const float*)d_in[3];
    const int*   edge_index  = (const int*)d_in[4];
    const float* sw1 = (const float*)d_in[5];
    const float* sb1 = (const float*)d_in[6];
    const float* sw2 = (const float*)d_in[7];
    const float* sb2 = (const float*)d_in[8];
    const float* vw1 = (const float*)d_in[9];
    const float* vb1 = (const float*)d_in[10];
    const float* vw2 = (const float*)d_in[11];
    const float* vb2 = (const float*)d_in[12];

    const int N = in_sizes[0] / HIDDEN;       // 50000
    const int E = in_sizes[4] / 2;            // 500000

    float* out_scalar = (float*)d_out;
    float* out_vector = (float*)d_out + (size_t)N * HIDDEN;

    // ---- workspace layout ----
    size_t off = 0;
    unsigned short* W = (unsigned short*)d_ws;           // [E,128] bf16 = 128 MB
    off += (size_t)E * 128 * 2;
    int* cols = (int*)((char*)d_ws + off);               // [E] = 2 MB
    off += (size_t)E * 4;
    int* eperm = (int*)((char*)d_ws + off);              // [E] = 2 MB
    off += (size_t)E * 4;
    int* ib = (int*)((char*)d_ws + off);
    int* counts    = ib;                                  // [N]
    int* partial   = ib + N;                              // [N]
    int* offsets   = ib + 2 * N;                          // [N+1]
    int* cursors   = ib + 3 * N + 1;                      // [N]
    int* blocksums = ib + 4 * N + 1;                      // [64]
    off += ((size_t)4 * N + 1 + 64) * 4;
    off = (off + 15) & ~(size_t)15;
    ushort4* feat = (ushort4*)((char*)d_ws + off);        // [N*64] = 25.6 MB
    const bool use_feat = (off + (size_t)N * 64 * 8) <= ws_size;

    hipMemsetAsync(counts, 0, (size_t)N * sizeof(int), stream);

    const int egrid = (E + 255) / 256;

    // featpack + fused histogram (hist always runs; feat write only if it fits)
    {
        const int total = N * 64;
        int cover = total > E ? total : E;
        featpack_kernel<<<(cover + 255) / 256, 256, 0, stream>>>(
            scalar, vector, edge_index, counts, feat, total, E, use_feat ? 1 : 0);
    }

    // CSR scan (3-pass, multi-block) + scatter (produces cols + forward perm)
    const int nb = (N + SCAN_BLOCK - 1) / SCAN_BLOCK;     // 49 (<=64 for pass2)
    scan_pass1<<<nb, SCAN_BLOCK, 0, stream>>>(counts, partial, blocksums, N);
    scan_pass2<<<1, 64, 0, stream>>>(blocksums, nb);
    scan_pass3<<<nb, SCAN_BLOCK, 0, stream>>>(partial, blocksums, offsets, cursors, N, E);
    scatter_kernel<<<egrid, 256, 0, stream>>>(edge_index, cursors, cols, eperm, E);

    // Phase A: MLP via MFMA over CSR slots; gathered reads, sequential writes.
    const int nchunks = (E + 63) / 64;
    mlp_mfma_kernel<<<1024, 256, 0, stream>>>(
        edge_length, eperm,
        sw1, sb1, sw2, sb2, vw1, vb1, vw2, vb2,
        W, E, nchunks);

    // Phase B: sequential W streaming, chase-free gathers.
    const int ngrid = (N + 3) / 4;
    if (use_feat) {
        node_kernel_feat<<<ngrid, 256, 0, stream>>>(
            feat, offsets, cols, W, out_scalar, out_vector, N);
    } else {
        node_kernel_f32<<<ngrid, 256, 0, stream>>>(
            scalar, vector, offsets, cols, W, out_scalar, out_vector, N);
    }
}